// Round 2
// baseline (245.082 us; speedup 1.0000x reference)
//
#include <hip/hip_runtime.h>
#include <hip/hip_bf16.h>
#include <stdint.h>

#define B_ROWS 4096
#define L_FEAT 256
#define VOCAB  8192

#define BM 128
#define BN 128
#define BK 64            // int8 MFMA K
#define NSTEP (VOCAB / BK)   // 128

typedef __attribute__((ext_vector_type(4))) int   intx4;
typedef __attribute__((ext_vector_type(4))) float floatx4;

__device__ __forceinline__ void async_copy16(const void* gsrc, void* ldst) {
  __builtin_amdgcn_global_load_lds(
      (const __attribute__((address_space(1))) void*)gsrc,
      (__attribute__((address_space(3))) void*)ldst, 16, 0, 0);
}

// ---------------- kernel 1: fused zero+scatter+sizes -------------------------
// One block per row: build the 8KB presence row in LDS (zero -> scatter bytes),
// then write it out coalesced (uint4) while popcounting for the row size.
__global__ __launch_bounds__(256) void presence_kernel(
    const int* __restrict__ f,
    unsigned char* __restrict__ P,
    float* __restrict__ sizes) {
  __shared__ __align__(16) unsigned char row_p[VOCAB];  // 8 KB
  const int row = blockIdx.x;
  const int tid = threadIdx.x;

  uint4* rp4 = (uint4*)row_p;
  const uint4 z = make_uint4(0u, 0u, 0u, 0u);
  #pragma unroll
  for (int j = 0; j < 2; ++j) rp4[tid + j * 256] = z;   // 512 uint4 = 8 KB
  __syncthreads();

  const int v = f[row * L_FEAT + tid];  // one feature per thread
  row_p[v] = 1;                         // duplicates benign
  __syncthreads();

  int cnt = 0;
  uint4* op4 = (uint4*)(P + (size_t)row * VOCAB);
  #pragma unroll
  for (int j = 0; j < 2; ++j) {
    const uint4 x = rp4[tid + j * 256];
    op4[tid + j * 256] = x;
    cnt += __popc(x.x) + __popc(x.y) + __popc(x.z) + __popc(x.w);
  }
  #pragma unroll
  for (int off = 32; off > 0; off >>= 1) cnt += __shfl_down(cnt, off);
  __shared__ int ws[4];
  if ((tid & 63) == 0) ws[tid >> 6] = cnt;
  __syncthreads();
  if (tid == 0) sizes[row] = (float)(ws[0] + ws[1] + ws[2] + ws[3]);
}

// ---------------- kernel 2: inter = P·P^T (i8 MFMA) + Jaccard + mirror -------
// 128x128 tile, BK=64, 4 waves in 2x2, each wave 4x4 of mfma_i32_16x16x64_i8.
// Round-2 changes (T3/T4/T5/T1):
//   * 4-buffer LDS pipeline, prefetch depth 2, ONE raw s_barrier per K-step,
//     counted `s_waitcnt vmcnt(8)` (never 0 in the loop) so 8 global_load_lds
//     stay in flight ACROSS the barrier. Safety: stage(i) writes the buffer
//     read at iter i-2; barrier i-1 separates those reads (lgkm-complete
//     before their MFMAs) from this write.
//   * setprio(1) around the MFMA cluster (waves now have role diversity).
//   * XCD-aware block swizzle (528 = 8*66, divisible -> simple form is
//     bijective): same-strip blocks share an XCD's L2 -> A-panel stays hot.
//   * nontemporal out stores: keep P resident in L3 (out is never re-read).
__global__ __launch_bounds__(256) void gemm_kernel(
    const unsigned char* __restrict__ P,
    const float* __restrict__ sizes,
    float* __restrict__ out) {
  // XCD swizzle then decode linear triangle index -> (by, bx), bx >= by
  int bid = blockIdx.x;
  bid = (bid & 7) * 66 + (bid >> 3);
  int b = bid, by = 0, rem = 32;
  while (b >= rem) { b -= rem; ++by; --rem; }
  const int bx = by + b;
  const int iBase = by * BM;   // output rows
  const int jBase = bx * BN;   // output cols

  __shared__ __align__(16) unsigned char As[4][BM * BK];  // 4 x 8 KB
  __shared__ __align__(16) unsigned char Bs[4][BN * BK];  // 4 x 8 KB

  const int tid  = threadIdx.x;
  const int wave = tid >> 6, lane = tid & 63;
  const int wm = wave >> 1, wn = wave & 1;   // 2x2 wave grid, each wave 64x64
  const int col16 = lane & 15, quad = lane >> 4;

  intx4 acc[4][4];
  #pragma unroll
  for (int a = 0; a < 4; ++a)
    #pragma unroll
    for (int c = 0; c < 4; ++c) acc[a][c] = (intx4){0, 0, 0, 0};

  // staging geometry: chunk = 16 rows x 64 cols = 1 KB; lane l -> row l>>2,
  // LDS slot (l&3), dst = chunk_base + lane*16 (linear, wave-uniform base).
  // Source chunk is PRE-SWIZZLED (involution) so ds_read side can XOR-swizzle.
  const int srow = lane >> 2;                          // 0..15 within chunk
  const int scol = ((lane & 3) ^ ((lane >> 3) & 3)) * 16;

  #define STAGE(buf, k0)                                                      \
    {                                                                         \
      _Pragma("unroll")                                                       \
      for (int t = 0; t < 2; ++t) {                                           \
        const int c = wave + t * 4;       /* chunk 0..7 */                    \
        const int r = c * 16 + srow;      /* tile row 0..127 */               \
        async_copy16(P + (size_t)(iBase + r) * VOCAB + (k0) + scol,           \
                     &As[buf][c * 1024]);                                     \
        async_copy16(P + (size_t)(jBase + r) * VOCAB + (k0) + scol,           \
                     &Bs[buf][c * 1024]);                                     \
      }                                                                       \
    }

  STAGE(0, 0);        // prologue: depth-2 prefetch
  STAGE(1, BK);

  const int sw = (col16 >> 1) & 3;  // read-side swizzle == (row>>1)&3

  for (int i = 0; i < NSTEP; ++i) {
    // prefetch k-step i+2 (wraps harmlessly past the end -> uniform waits)
    const int kpre = ((i + 2) * BK) & (VOCAB - 1);
    STAGE((i + 2) & 3, kpre);

    // stage(i) must be complete; stages i+1, i+2 (8 loads) stay in flight
    asm volatile("s_waitcnt vmcnt(8)" ::: "memory");
    __builtin_amdgcn_s_barrier();

    const unsigned char* Ab = As[i & 3];
    const unsigned char* Bb = Bs[i & 3];
    intx4 a[4], bfr[4];
    #pragma unroll
    for (int tm = 0; tm < 4; ++tm)
      a[tm] = *(const intx4*)&Ab[(wm * 64 + tm * 16 + col16) * BK +
                                 (quad ^ sw) * 16];
    #pragma unroll
    for (int tn = 0; tn < 4; ++tn)
      bfr[tn] = *(const intx4*)&Bb[(wn * 64 + tn * 16 + col16) * BK +
                                   (quad ^ sw) * 16];

    __builtin_amdgcn_s_setprio(1);
    #pragma unroll
    for (int tm = 0; tm < 4; ++tm)
      #pragma unroll
      for (int tn = 0; tn < 4; ++tn)
        acc[tm][tn] = __builtin_amdgcn_mfma_i32_16x16x64_i8(
            a[tm], bfr[tn], acc[tm][tn], 0, 0, 0);
    __builtin_amdgcn_s_setprio(0);
  }

  // epilogue: sim = -inter / (|A_i| + |A_j| - inter); write value + mirror.
  // nontemporal: out is write-only -> don't evict P from L2/L3.
  #pragma unroll
  for (int tm = 0; tm < 4; ++tm) {
    const int rowb = iBase + wm * 64 + tm * 16 + quad * 4;
    const float si0 = sizes[rowb + 0], si1 = sizes[rowb + 1];
    const float si2 = sizes[rowb + 2], si3 = sizes[rowb + 3];
    #pragma unroll
    for (int tn = 0; tn < 4; ++tn) {
      const int col = jBase + wn * 64 + tn * 16 + col16;
      const float sj = sizes[col];
      floatx4 tv;
      {
        const float inter = (float)acc[tm][tn][0];
        const float u = si0 + sj - inter;
        tv[0] = (u != 0.f) ? (-inter / u) : 0.f;
      }
      {
        const float inter = (float)acc[tm][tn][1];
        const float u = si1 + sj - inter;
        tv[1] = (u != 0.f) ? (-inter / u) : 0.f;
      }
      {
        const float inter = (float)acc[tm][tn][2];
        const float u = si2 + sj - inter;
        tv[2] = (u != 0.f) ? (-inter / u) : 0.f;
      }
      {
        const float inter = (float)acc[tm][tn][3];
        const float u = si3 + sj - inter;
        tv[3] = (u != 0.f) ? (-inter / u) : 0.f;
      }
      // upper-triangle tile element (row-major, 4 scalar rows at fixed col)
      __builtin_nontemporal_store(tv[0], &out[(size_t)(rowb + 0) * B_ROWS + col]);
      __builtin_nontemporal_store(tv[1], &out[(size_t)(rowb + 1) * B_ROWS + col]);
      __builtin_nontemporal_store(tv[2], &out[(size_t)(rowb + 2) * B_ROWS + col]);
      __builtin_nontemporal_store(tv[3], &out[(size_t)(rowb + 3) * B_ROWS + col]);
      // mirrored element: 4 row-values are contiguous in the transposed row
      __builtin_nontemporal_store(tv, (floatx4*)&out[(size_t)col * B_ROWS + rowb]);
    }
  }
}

// ---------------- launcher ---------------------------------------------------
extern "C" void kernel_launch(void* const* d_in, const int* in_sizes, int n_in,
                              void* d_out, int out_size, void* d_ws, size_t ws_size,
                              hipStream_t stream) {
  const int* features = (const int*)d_in[0];
  float* out = (float*)d_out;
  unsigned char* P = (unsigned char*)d_ws;                        // 32 MB int8
  float* sizes = (float*)((char*)d_ws + (size_t)B_ROWS * VOCAB);  // +16 KB

  presence_kernel<<<B_ROWS, 256, 0, stream>>>(features, P, sizes);
  gemm_kernel<<<528, 256, 0, stream>>>(P, sizes, out);
}

// Round 3
// 181.631 us; speedup vs baseline: 1.3493x; 1.3493x over previous
//
#include <hip/hip_runtime.h>
#include <hip/hip_bf16.h>
#include <stdint.h>

#define B_ROWS 4096
#define L_FEAT 256
#define VOCAB  8192

#define BM 128
#define BN 128
#define BK 64            // int8 MFMA K
#define NSTEP (VOCAB / BK)   // 128

typedef __attribute__((ext_vector_type(4))) int   intx4;
typedef __attribute__((ext_vector_type(4))) float floatx4;

__device__ __forceinline__ void async_copy16(const void* gsrc, void* ldst) {
  __builtin_amdgcn_global_load_lds(
      (const __attribute__((address_space(1))) void*)gsrc,
      (__attribute__((address_space(3))) void*)ldst, 16, 0, 0);
}

// ---------------- kernel 1: fused zero+scatter+sizes -------------------------
__global__ __launch_bounds__(256) void presence_kernel(
    const int* __restrict__ f,
    unsigned char* __restrict__ P,
    float* __restrict__ sizes) {
  __shared__ __align__(16) unsigned char row_p[VOCAB];  // 8 KB
  const int row = blockIdx.x;
  const int tid = threadIdx.x;

  uint4* rp4 = (uint4*)row_p;
  const uint4 z = make_uint4(0u, 0u, 0u, 0u);
  #pragma unroll
  for (int j = 0; j < 2; ++j) rp4[tid + j * 256] = z;   // 512 uint4 = 8 KB
  __syncthreads();

  const int v = f[row * L_FEAT + tid];  // one feature per thread
  row_p[v] = 1;                         // duplicates benign
  __syncthreads();

  int cnt = 0;
  uint4* op4 = (uint4*)(P + (size_t)row * VOCAB);
  #pragma unroll
  for (int j = 0; j < 2; ++j) {
    const uint4 x = rp4[tid + j * 256];
    op4[tid + j * 256] = x;
    cnt += __popc(x.x) + __popc(x.y) + __popc(x.z) + __popc(x.w);
  }
  #pragma unroll
  for (int off = 32; off > 0; off >>= 1) cnt += __shfl_down(cnt, off);
  __shared__ int ws[4];
  if ((tid & 63) == 0) ws[tid >> 6] = cnt;
  __syncthreads();
  if (tid == 0) sizes[row] = (float)(ws[0] + ws[1] + ws[2] + ws[3]);
}

// ---------------- kernel 2: inter = P·P^T (i8 MFMA) + Jaccard + mirror -------
// 128x128 tile, BK=64, 4 waves in 2x2, each wave 4x4 of mfma_i32_16x16x64_i8.
// Round-3 change: 3-buffer LDS (48 KB -> 3 blocks/CU, ALL 528 blocks resident,
// no 16-block serial tail that cost round-2 ~half its time). Depth-2 prefetch
// kept; STAGE(i+2) moved AFTER barrier(i) which makes 3 buffers race-free:
//   stage(i+2) writes buf (i-1)%3; every wave's reads of that buf (iter i-1)
//   are lgkm-complete before it reaches barrier(i).
// Wait: vmcnt(4) at top of iter i -> stage(i) landed, stage(i+1)'s 4 loads
// stay in flight across the barrier (never drained to 0 in the loop).
__global__ __launch_bounds__(256) void gemm_kernel(
    const unsigned char* __restrict__ P,
    const float* __restrict__ sizes,
    float* __restrict__ out) {
  // XCD swizzle (528 = 8*66 -> bijective) then triangle decode, bx >= by
  int bid = blockIdx.x;
  bid = (bid & 7) * 66 + (bid >> 3);
  int b = bid, by = 0, rem = 32;
  while (b >= rem) { b -= rem; ++by; --rem; }
  const int bx = by + b;
  const int iBase = by * BM;   // output rows
  const int jBase = bx * BN;   // output cols

  __shared__ __align__(16) unsigned char As[3][BM * BK];  // 3 x 8 KB
  __shared__ __align__(16) unsigned char Bs[3][BN * BK];  // 3 x 8 KB

  const int tid  = threadIdx.x;
  const int wave = tid >> 6, lane = tid & 63;
  const int wm = wave >> 1, wn = wave & 1;   // 2x2 wave grid, each wave 64x64
  const int col16 = lane & 15, quad = lane >> 4;

  intx4 acc[4][4];
  #pragma unroll
  for (int a = 0; a < 4; ++a)
    #pragma unroll
    for (int c = 0; c < 4; ++c) acc[a][c] = (intx4){0, 0, 0, 0};

  // staging geometry: chunk = 16 rows x 64 cols = 1 KB; lane l -> row l>>2,
  // LDS slot (l&3), dst = chunk_base + lane*16 (linear, wave-uniform base).
  // Source chunk PRE-SWIZZLED (involution) so the ds_read side can XOR-swizzle.
  const int srow = lane >> 2;                          // 0..15 within chunk
  const int scol = ((lane & 3) ^ ((lane >> 3) & 3)) * 16;

  #define STAGE(buf, k0)                                                      \
    {                                                                         \
      _Pragma("unroll")                                                       \
      for (int t = 0; t < 2; ++t) {                                           \
        const int c = wave + t * 4;       /* chunk 0..7 */                    \
        const int r = c * 16 + srow;      /* tile row 0..127 */               \
        async_copy16(P + (size_t)(iBase + r) * VOCAB + (k0) + scol,           \
                     &As[buf][c * 1024]);                                     \
        async_copy16(P + (size_t)(jBase + r) * VOCAB + (k0) + scol,           \
                     &Bs[buf][c * 1024]);                                     \
      }                                                                       \
    }

  STAGE(0, 0);        // prologue: depth-2 prefetch
  STAGE(1, BK);

  const int sw = (col16 >> 1) & 3;  // read-side swizzle == (row>>1)&3

  int cur = 0, pre = 2;             // read buf, prefetch-dest buf (cur+2 mod 3)
  for (int i = 0; i < NSTEP; ++i) {
    // stage(i) must be landed; stage(i+1) stays in flight across the barrier
    asm volatile("s_waitcnt vmcnt(4)" ::: "memory");
    __builtin_amdgcn_s_barrier();

    // prefetch k-step i+2 (wraps harmlessly past the end -> uniform waits)
    const int kpre = ((i + 2) * BK) & (VOCAB - 1);
    STAGE(pre, kpre);

    const unsigned char* Ab = As[cur];
    const unsigned char* Bb = Bs[cur];
    intx4 a[4], bfr[4];
    #pragma unroll
    for (int tm = 0; tm < 4; ++tm)
      a[tm] = *(const intx4*)&Ab[(wm * 64 + tm * 16 + col16) * BK +
                                 (quad ^ sw) * 16];
    #pragma unroll
    for (int tn = 0; tn < 4; ++tn)
      bfr[tn] = *(const intx4*)&Bb[(wn * 64 + tn * 16 + col16) * BK +
                                   (quad ^ sw) * 16];

    __builtin_amdgcn_s_setprio(1);
    #pragma unroll
    for (int tm = 0; tm < 4; ++tm)
      #pragma unroll
      for (int tn = 0; tn < 4; ++tn)
        acc[tm][tn] = __builtin_amdgcn_mfma_i32_16x16x64_i8(
            a[tm], bfr[tn], acc[tm][tn], 0, 0, 0);
    __builtin_amdgcn_s_setprio(0);

    cur = (cur == 2) ? 0 : cur + 1;
    pre = (pre == 2) ? 0 : pre + 1;
  }

  // epilogue: sim = -inter / (|A_i| + |A_j| - inter); write value + mirror.
  // nontemporal: out is write-only -> don't evict P from L2/L3.
  #pragma unroll
  for (int tm = 0; tm < 4; ++tm) {
    const int rowb = iBase + wm * 64 + tm * 16 + quad * 4;
    const float si0 = sizes[rowb + 0], si1 = sizes[rowb + 1];
    const float si2 = sizes[rowb + 2], si3 = sizes[rowb + 3];
    #pragma unroll
    for (int tn = 0; tn < 4; ++tn) {
      const int col = jBase + wn * 64 + tn * 16 + col16;
      const float sj = sizes[col];
      floatx4 tv;
      {
        const float inter = (float)acc[tm][tn][0];
        const float u = si0 + sj - inter;
        tv[0] = (u != 0.f) ? (-inter / u) : 0.f;
      }
      {
        const float inter = (float)acc[tm][tn][1];
        const float u = si1 + sj - inter;
        tv[1] = (u != 0.f) ? (-inter / u) : 0.f;
      }
      {
        const float inter = (float)acc[tm][tn][2];
        const float u = si2 + sj - inter;
        tv[2] = (u != 0.f) ? (-inter / u) : 0.f;
      }
      {
        const float inter = (float)acc[tm][tn][3];
        const float u = si3 + sj - inter;
        tv[3] = (u != 0.f) ? (-inter / u) : 0.f;
      }
      // upper-triangle tile element (row-major, 4 scalar rows at fixed col)
      __builtin_nontemporal_store(tv[0], &out[(size_t)(rowb + 0) * B_ROWS + col]);
      __builtin_nontemporal_store(tv[1], &out[(size_t)(rowb + 1) * B_ROWS + col]);
      __builtin_nontemporal_store(tv[2], &out[(size_t)(rowb + 2) * B_ROWS + col]);
      __builtin_nontemporal_store(tv[3], &out[(size_t)(rowb + 3) * B_ROWS + col]);
      // mirrored element: 4 row-values are contiguous in the transposed row
      __builtin_nontemporal_store(tv, (floatx4*)&out[(size_t)col * B_ROWS + rowb]);
    }
  }
}

// ---------------- launcher ---------------------------------------------------
extern "C" void kernel_launch(void* const* d_in, const int* in_sizes, int n_in,
                              void* d_out, int out_size, void* d_ws, size_t ws_size,
                              hipStream_t stream) {
  const int* features = (const int*)d_in[0];
  float* out = (float*)d_out;
  unsigned char* P = (unsigned char*)d_ws;                        // 32 MB int8
  float* sizes = (float*)((char*)d_ws + (size_t)B_ROWS * VOCAB);  // +16 KB

  presence_kernel<<<B_ROWS, 256, 0, stream>>>(features, P, sizes);
  gemm_kernel<<<528, 256, 0, stream>>>(P, sizes, out);
}